// Round 8
// baseline (624.954 us; speedup 1.0000x reference)
//
#include <hip/hip_runtime.h>

#define T_LEN 1024
#define HID   32
#define LDIM  16
#define BATCH 512
#define NB    16           // batch elems per block
#define NT    384          // 6 waves: (layer 0..2) x (unit-half 0..1)
#define ROWB  80           // LDS bytes per n-row of h (64 data + 16 pad; 16B aligned, bank-spread)
#define LAYB  (16 * ROWB)  // per (parity, layer) region
#define LOG2E 1.44269504f

typedef _Float16 half8  __attribute__((ext_vector_type(8)));
typedef _Float16 half2v __attribute__((ext_vector_type(2)));
typedef float    f32x4  __attribute__((ext_vector_type(4)));
typedef unsigned u32;
typedef unsigned u32x4  __attribute__((ext_vector_type(4)));
typedef unsigned u32x2  __attribute__((ext_vector_type(2)));

#if defined(__has_builtin)
#if __has_builtin(__builtin_amdgcn_rcpf)
#define FAST_RCP(x) __builtin_amdgcn_rcpf(x)
#endif
#if __has_builtin(__builtin_amdgcn_exp2f)
#define FAST_EXP2(x) __builtin_amdgcn_exp2f(x)
#endif
#endif
#ifndef FAST_RCP
#define FAST_RCP(x) (1.0f / (x))
#endif
#ifndef FAST_EXP2
#define FAST_EXP2(x) __expf(0.69314718f * (x))
#endif

#define MFMA(a, b, c) __builtin_amdgcn_mfma_f32_16x16x32_f16((a), (b), (c), 0, 0, 0)

__global__ __launch_bounds__(NT, 1)
void lstm_encoder_kernel(const float* __restrict__ x,
                         const float* __restrict__ Wih0, const float* __restrict__ Whh0,
                         const float* __restrict__ bih0, const float* __restrict__ bhh0,
                         const float* __restrict__ Wih1, const float* __restrict__ Whh1,
                         const float* __restrict__ bih1, const float* __restrict__ bhh1,
                         const float* __restrict__ Wih2, const float* __restrict__ Whh2,
                         const float* __restrict__ bih2, const float* __restrict__ bhh2,
                         const float* __restrict__ Wm,  const float* __restrict__ bm,
                         const float* __restrict__ Wlv, const float* __restrict__ blv,
                         float* __restrict__ out)
{
    const int b0   = blockIdx.x * NB;
    const int tid  = threadIdx.x;
    const int lane = tid & 63;
    const int wave = tid >> 6;        // 0..5
    const int l    = wave >> 1;       // layer (wave-uniform)
    const int wv   = wave & 1;        // unit-half: units [wv*16, wv*16+16)
    const int n    = lane & 15;       // batch elem (MFMA col) / A-frag row
    const int kc   = lane >> 4;       // 0..3: k-chunk-of-8 / D-row quad

    // h double-buffer: [parity][layer][n:16][k:32 h2 + pad], 80B rows
    __shared__ __align__(16) unsigned char hb_flat[2 * 3 * LAYB];  // 7680 B
    __shared__ float cbuf[NB * HID];                               // final c3

    for (int i = tid; i < (int)(sizeof(hb_flat) / 4); i += NT) ((u32*)hb_flat)[i] = 0u;

    // ---- weight fragments (A) + bias, loaded once, exp2-prescaled ----
    const float* Wih = (l == 0) ? Wih0 : (l == 1) ? Wih1 : Wih2;
    const float* Whh = (l == 0) ? Whh0 : (l == 1) ? Whh1 : Whh2;
    const float* bih = (l == 0) ? bih0 : (l == 1) ? bih1 : bih2;
    const float* bhh = (l == 0) ? bhh0 : (l == 1) ? bhh1 : bhh2;

    // K layout: l>=1: [h_{l-1}(k0-31) | h_l(k32-63)] -> A chunks [Wih | Whh]
    //           l==0: [h_0(k0-31) | x(k32,33), 0...] -> A chunks [Whh | Wx-padded]
    half8 af[4][2];     // [gate tile i,f,g,o][k-chunk]
    f32x4 biasC[4];     // per-cell bias as MFMA C-input
#pragma unroll
    for (int tau = 0; tau < 4; ++tau) {
        const int   R  = tau * HID + wv * 16 + n;   // A row = lane&15
        const float sc = (tau == 2) ? (2.0f * LOG2E) : LOG2E;  // g-rows get 2x
#pragma unroll
        for (int i2 = 0; i2 < 8; ++i2) {
            const int kk = kc * 8 + i2;             // k within 32-col chunk
            const float w0 = (l == 0) ? Whh[R * HID + kk] : Wih[R * HID + kk];
            const float w1 = (l == 0) ? ((kk < 2) ? Wih[R * 2 + kk] : 0.0f)
                                      : Whh[R * HID + kk];
            af[tau][0][i2] = (_Float16)(w0 * sc);
            af[tau][1][i2] = (_Float16)(w1 * sc);
        }
#pragma unroll
        for (int r = 0; r < 4; ++r) {
            const int rr = tau * HID + wv * 16 + kc * 4 + r;  // D row = kc*4+r
            biasC[tau][r] = (bih[rr] + bhh[rr]) * sc;
        }
    }

    // ---- LDS offsets (parity added with literal in STEP) ----
    const int off_r0 = ((l == 0) ? 0 : (l - 1)) * LAYB + n * ROWB + kc * 16;
    const int off_r1 = l * LAYB + n * ROWB + kc * 16;
    const int off_w  = l * LAYB + n * ROWB + (wv * 16 + kc * 4) * 2;

    // ---- x prefetch pipeline (layer-0 waves, lanes kc==0), distance ~4 steps ----
    const float2* xb2 = (const float2*)(x + (size_t)(b0 + n) * (T_LEN * 2));
    const bool xldr = (l == 0) && (kc == 0);
    float2 xp0, xp1, xp2, xp3;
    if (xldr) { xp0 = xb2[0]; xp1 = xb2[1]; xp2 = xb2[2]; xp3 = xb2[3]; }

    float cc[4] = {0.f, 0.f, 0.f, 0.f};  // cell state: (unit wv*16+kc*4+r, elem n)

    __syncthreads();

#define STEP(P, S, XP)                                                           \
    do {                                                                         \
        const int t_ = (S) - l;                                                  \
        if ((unsigned)t_ < (unsigned)T_LEN) {                                    \
            half8 bf0 = __builtin_bit_cast(half8,                                \
                *(const u32x4*)(hb_flat + (P) * (3 * LAYB) + off_r0));           \
            half8 bf1;                                                           \
            if (l == 0) {                                                        \
                half8 z = {0, 0, 0, 0, 0, 0, 0, 0};                              \
                if (kc == 0) { z[0] = (_Float16)XP.x; z[1] = (_Float16)XP.y; }   \
                bf1 = z;                                                         \
            } else {                                                             \
                bf1 = __builtin_bit_cast(half8,                                  \
                    *(const u32x4*)(hb_flat + (P) * (3 * LAYB) + off_r1));       \
            }                                                                    \
            f32x4 ac0 = MFMA(af[0][0], bf0, biasC[0]);                           \
            f32x4 ac1 = MFMA(af[1][0], bf0, biasC[1]);                           \
            f32x4 ac2 = MFMA(af[2][0], bf0, biasC[2]);                           \
            f32x4 ac3 = MFMA(af[3][0], bf0, biasC[3]);                           \
            ac0 = MFMA(af[0][1], bf1, ac0);                                      \
            ac1 = MFMA(af[1][1], bf1, ac1);                                      \
            ac2 = MFMA(af[2][1], bf1, ac2);                                      \
            ac3 = MFMA(af[3][1], bf1, ac3);                                      \
            float hv[4];                                                         \
            _Pragma("unroll")                                                    \
            for (int r = 0; r < 4; ++r) {                                        \
                const float ei = FAST_EXP2(-ac0[r]);  /* i pre-scaled log2e  */  \
                const float ef = FAST_EXP2(-ac1[r]);                             \
                const float eg = FAST_EXP2(-ac2[r]);  /* g pre-scaled 2log2e */  \
                const float eo = FAST_EXP2(-ac3[r]);                             \
                const float ig = (1.0f - eg) *                                   \
                                 FAST_RCP((1.0f + ei) * (1.0f + eg));            \
                const float fv = FAST_RCP(1.0f + ef);                            \
                float c_ = fmaf(fv, cc[r], ig);                                  \
                c_ = fminf(fmaxf(c_, -20.0f), 20.0f);                            \
                cc[r] = c_;                                                      \
                const float ec = FAST_EXP2(-2.0f * LOG2E * c_);                  \
                hv[r] = (1.0f - ec) *                                            \
                        FAST_RCP((1.0f + eo) * (1.0f + ec)); /* o*tanh(c) */     \
            }                                                                    \
            half2v p01, p23;                                                     \
            p01[0] = (_Float16)hv[0]; p01[1] = (_Float16)hv[1];                  \
            p23[0] = (_Float16)hv[2]; p23[1] = (_Float16)hv[3];                  \
            u32x2 wpk;                                                           \
            wpk[0] = __builtin_bit_cast(u32, p01);                               \
            wpk[1] = __builtin_bit_cast(u32, p23);                               \
            *(u32x2*)(hb_flat + ((P) ^ 1) * (3 * LAYB) + off_w) = wpk;           \
        }                                                                        \
        __syncthreads();                                                         \
    } while (0)

    for (int s = 0; s < T_LEN + 2; s += 2) {
        STEP(0, s, xp0);
        STEP(1, s + 1, xp1);
        if (xldr) {
            xp0 = xp2; xp1 = xp3;
            const int t4 = (s + 4 < T_LEN) ? s + 4 : T_LEN - 1;
            const int t5 = (s + 5 < T_LEN) ? s + 5 : T_LEN - 1;
            xp2 = xb2[t4]; xp3 = xb2[t5];
        }
    }
#undef STEP

    // ---- final c3 of layer 2 -> LDS ----
    if (l == 2) {
        float* cp = cbuf + n * HID + wv * 16 + kc * 4;
        cp[0] = cc[0]; cp[1] = cc[1]; cp[2] = cc[2]; cp[3] = cc[3];
    }
    __syncthreads();

    // ---- projection: mean / log_var ----
    for (int v = tid; v < NB * 2 * LDIM; v += NT) {
        const int  nn = v >> 5;
        const int  o  = v & 31;
        const bool is_mean = (o < LDIM);
        const int  jo = o & (LDIM - 1);
        const float* W  = is_mean ? Wm : Wlv;
        float acc = is_mean ? bm[jo] : blv[jo];
#pragma unroll
        for (int k = 0; k < HID; ++k) acc = fmaf(W[jo * HID + k], cbuf[nn * HID + k], acc);
        out[(is_mean ? 0 : (size_t)BATCH * LDIM) + (size_t)(b0 + nn) * LDIM + jo] = acc;
    }
}

extern "C" void kernel_launch(void* const* d_in, const int* in_sizes, int n_in,
                              void* d_out, int out_size, void* d_ws, size_t ws_size,
                              hipStream_t stream) {
    const float* x    = (const float*)d_in[0];
    const float* Wih0 = (const float*)d_in[1];
    const float* Whh0 = (const float*)d_in[2];
    const float* bih0 = (const float*)d_in[3];
    const float* bhh0 = (const float*)d_in[4];
    const float* Wih1 = (const float*)d_in[5];
    const float* Whh1 = (const float*)d_in[6];
    const float* bih1 = (const float*)d_in[7];
    const float* bhh1 = (const float*)d_in[8];
    const float* Wih2 = (const float*)d_in[9];
    const float* Whh2 = (const float*)d_in[10];
    const float* bih2 = (const float*)d_in[11];
    const float* bhh2 = (const float*)d_in[12];
    const float* Wm   = (const float*)d_in[13];
    const float* bm   = (const float*)d_in[14];
    const float* Wlv  = (const float*)d_in[15];
    const float* blv  = (const float*)d_in[16];
    float* out = (float*)d_out;

    lstm_encoder_kernel<<<dim3(BATCH / NB), dim3(NT), 0, stream>>>(
        x, Wih0, Whh0, bih0, bhh0, Wih1, Whh1, bih1, bhh1,
        Wih2, Whh2, bih2, bhh2, Wm, bm, Wlv, blv, out);
}

// Round 9
// 610.712 us; speedup vs baseline: 1.0233x; 1.0233x over previous
//
#include <hip/hip_runtime.h>

#define T_LEN 1024
#define HID   32
#define LDIM  16
#define BATCH 512
#define NB    16           // batch elems per block (MFMA N)
#define NT    384          // 6 waves: (layer 0..2) x (unit-half 0..1)
#define ROWB  80           // LDS bytes per n-row (64 data + 16 pad)
#define LAYB  (16 * ROWB)  // per-slot bytes (16 n-rows)
#define SLOTS 4            // h0, h1, h2, xslot
#define PARB  (SLOTS * LAYB)
#define LOG2E 1.44269504f

typedef _Float16 half8  __attribute__((ext_vector_type(8)));
typedef _Float16 half2v __attribute__((ext_vector_type(2)));
typedef float    f32x4  __attribute__((ext_vector_type(4)));
typedef unsigned u32;
typedef unsigned u32x4  __attribute__((ext_vector_type(4)));
typedef unsigned u32x2  __attribute__((ext_vector_type(2)));

#if defined(__has_builtin)
#if __has_builtin(__builtin_amdgcn_rcpf)
#define FAST_RCP(x) __builtin_amdgcn_rcpf(x)
#endif
#if __has_builtin(__builtin_amdgcn_exp2f)
#define FAST_EXP2(x) __builtin_amdgcn_exp2f(x)
#endif
#endif
#ifndef FAST_RCP
#define FAST_RCP(x) (1.0f / (x))
#endif
#ifndef FAST_EXP2
#define FAST_EXP2(x) __expf(0.69314718f * (x))
#endif

#define MFMA(a, b, c) __builtin_amdgcn_mfma_f32_16x16x32_f16((a), (b), (c), 0, 0, 0)

__global__ __launch_bounds__(NT, 1)
void lstm_encoder_kernel(const float* __restrict__ x,
                         const float* __restrict__ Wih0, const float* __restrict__ Whh0,
                         const float* __restrict__ bih0, const float* __restrict__ bhh0,
                         const float* __restrict__ Wih1, const float* __restrict__ Whh1,
                         const float* __restrict__ bih1, const float* __restrict__ bhh1,
                         const float* __restrict__ Wih2, const float* __restrict__ Whh2,
                         const float* __restrict__ bih2, const float* __restrict__ bhh2,
                         const float* __restrict__ Wm,  const float* __restrict__ bm,
                         const float* __restrict__ Wlv, const float* __restrict__ blv,
                         float* __restrict__ out)
{
    const int b0   = blockIdx.x * NB;
    const int tid  = threadIdx.x;
    const int lane = tid & 63;
    const int wave = tid >> 6;        // 0..5
    const int l    = wave >> 1;       // layer (wave-uniform)
    const int wv   = wave & 1;        // unit-half: units [wv*16, wv*16+16)
    const int n    = lane & 15;       // batch elem (MFMA col) / A-frag row
    const int kc   = lane >> 4;       // 0..3: k-chunk-of-8 / D-row quad

    // [parity][slot: h0,h1,h2,xslot][n:16][80B row]
    __shared__ __align__(16) unsigned char hb[2 * PARB];   // 10240 B
    __shared__ u32  xs[T_LEN * NB];                        // 64 KB: packed f16 x-pairs [t][n]
    __shared__ float cbuf[NB * HID];

    // ---- zero h/xslot buffers ----
    for (int i = tid; i < (int)(2 * PARB / 4); i += NT) ((u32*)hb)[i] = 0u;

    // ---- stage ALL x into LDS as f16 pairs (coalesced global reads) ----
    for (int i = tid; i < NB * T_LEN; i += NT) {
        const int nn = i >> 10, t = i & (T_LEN - 1);
        const float2 v = *(const float2*)(x + ((size_t)(b0 + nn) * T_LEN + t) * 2);
        half2v p; p[0] = (_Float16)v.x; p[1] = (_Float16)v.y;
        xs[t * NB + nn] = __builtin_bit_cast(u32, p);
    }

    // ---- weight fragments (A) + bias, loaded once, exp2-prescaled ----
    const float* Wih = (l == 0) ? Wih0 : (l == 1) ? Wih1 : Wih2;
    const float* Whh = (l == 0) ? Whh0 : (l == 1) ? Whh1 : Whh2;
    const float* bih = (l == 0) ? bih0 : (l == 1) ? bih1 : bih2;
    const float* bhh = (l == 0) ? bhh0 : (l == 1) ? bhh1 : bhh2;

    // K layout: chunk0 reads slotA = (l==0 ? xslot : h_{l-1}); chunk1 reads h_l.
    half8 af[4][2];     // [gate tile i,f,g,o][k-chunk]
    f32x4 biasC[4];     // per-cell bias as MFMA C-input
#pragma unroll
    for (int tau = 0; tau < 4; ++tau) {
        const int   R  = tau * HID + wv * 16 + n;   // A row = lane&15
        const float sc = (tau == 2) ? (2.0f * LOG2E) : LOG2E;  // g-rows get 2x
#pragma unroll
        for (int i2 = 0; i2 < 8; ++i2) {
            const int kk = kc * 8 + i2;             // k within 32-col chunk
            const float w0 = (l == 0) ? ((kk < 2) ? Wih[R * 2 + kk] : 0.0f)
                                      : Wih[R * HID + kk];
            const float w1 = Whh[R * HID + kk];
            af[tau][0][i2] = (_Float16)(w0 * sc);
            af[tau][1][i2] = (_Float16)(w1 * sc);
        }
#pragma unroll
        for (int r = 0; r < 4; ++r) {
            const int rr = tau * HID + wv * 16 + kc * 4 + r;  // D row = kc*4+r
            biasC[tau][r] = (bih[rr] + bhh[rr]) * sc;
        }
    }

    // ---- LDS offsets ----
    const int slotA  = (l == 0) ? 3 : (l - 1);
    const int off_r0 = slotA * LAYB + n * ROWB + kc * 16;
    const int off_r1 = l * LAYB + n * ROWB + kc * 16;
    const int off_w  = l * LAYB + n * ROWB + (wv * 16 + kc * 4) * 2;
    const int off_x  = 3 * LAYB + n * ROWB;   // xslot dword0 of row n

    const bool xf = (wave == 0) && (kc == 0);  // 16 x-feeder lanes (one per n)

    float cc[4] = {0.f, 0.f, 0.f, 0.f};  // cell state: (unit wv*16+kc*4+r, elem n)

    __syncthreads();
    if (tid < NB) *(u32*)(hb + off_x - n * ROWB + tid * ROWB) = xs[tid];  // parity0 xslot <- x_0
    __syncthreads();

#define STEP(P, S)                                                               \
    do {                                                                         \
        const int t_ = (S) - l;                                                  \
        if ((unsigned)t_ < (unsigned)T_LEN) {                                    \
            u32 xw = 0;                                                          \
            if (xf) {                                                            \
                const int tn = ((S) + 1 < T_LEN) ? (S) + 1 : T_LEN - 1;          \
                xw = xs[tn * NB + n];                                            \
            }                                                                    \
            const half8 bf0 = __builtin_bit_cast(half8,                          \
                *(const u32x4*)(hb + (P) * PARB + off_r0));                      \
            const half8 bf1 = __builtin_bit_cast(half8,                          \
                *(const u32x4*)(hb + (P) * PARB + off_r1));                      \
            f32x4 ac0 = MFMA(af[0][0], bf0, biasC[0]);                           \
            f32x4 ac1 = MFMA(af[1][0], bf0, biasC[1]);                           \
            f32x4 ac2 = MFMA(af[2][0], bf0, biasC[2]);                           \
            f32x4 ac3 = MFMA(af[3][0], bf0, biasC[3]);                           \
            ac0 = MFMA(af[0][1], bf1, ac0);                                      \
            ac1 = MFMA(af[1][1], bf1, ac1);                                      \
            ac2 = MFMA(af[2][1], bf1, ac2);                                      \
            ac3 = MFMA(af[3][1], bf1, ac3);                                      \
            float hv[4];                                                         \
            _Pragma("unroll")                                                    \
            for (int r = 0; r < 4; ++r) {                                        \
                const float ei = FAST_EXP2(-ac0[r]);  /* i pre-scaled log2e  */  \
                const float ef = FAST_EXP2(-ac1[r]);                             \
                const float eg = FAST_EXP2(-ac2[r]);  /* g pre-scaled 2log2e */  \
                const float eo = FAST_EXP2(-ac3[r]);                             \
                const float ig = (1.0f - eg) *                                   \
                                 FAST_RCP((1.0f + ei) * (1.0f + eg));            \
                const float fv = FAST_RCP(1.0f + ef);                            \
                float c_ = fmaf(fv, cc[r], ig);                                  \
                c_ = fminf(fmaxf(c_, -20.0f), 20.0f);                            \
                cc[r] = c_;                                                      \
                const float ec = FAST_EXP2(-2.0f * LOG2E * c_);                  \
                hv[r] = (1.0f - ec) *                                            \
                        FAST_RCP((1.0f + eo) * (1.0f + ec)); /* o*tanh(c) */     \
            }                                                                    \
            half2v p01, p23;                                                     \
            p01[0] = (_Float16)hv[0]; p01[1] = (_Float16)hv[1];                  \
            p23[0] = (_Float16)hv[2]; p23[1] = (_Float16)hv[3];                  \
            u32x2 wpk;                                                           \
            wpk[0] = __builtin_bit_cast(u32, p01);                               \
            wpk[1] = __builtin_bit_cast(u32, p23);                               \
            *(u32x2*)(hb + ((P) ^ 1) * PARB + off_w) = wpk;                      \
            if (xf) *(u32*)(hb + ((P) ^ 1) * PARB + off_x) = xw;                 \
        }                                                                        \
        __syncthreads();                                                         \
    } while (0)

    for (int s = 0; s < T_LEN + 2; s += 2) {
        STEP(0, s);
        STEP(1, s + 1);
    }
#undef STEP

    // ---- final c3 of layer 2 -> LDS ----
    if (l == 2) {
        float* cp = cbuf + n * HID + wv * 16 + kc * 4;
        cp[0] = cc[0]; cp[1] = cc[1]; cp[2] = cc[2]; cp[3] = cc[3];
    }
    __syncthreads();

    // ---- projection: mean / log_var ----
    for (int v = tid; v < NB * 2 * LDIM; v += NT) {
        const int  nn = v >> 5;
        const int  o  = v & 31;
        const bool is_mean = (o < LDIM);
        const int  jo = o & (LDIM - 1);
        const float* W  = is_mean ? Wm : Wlv;
        float acc = is_mean ? bm[jo] : blv[jo];
#pragma unroll
        for (int k = 0; k < HID; ++k) acc = fmaf(W[jo * HID + k], cbuf[nn * HID + k], acc);
        out[(is_mean ? 0 : (size_t)BATCH * LDIM) + (size_t)(b0 + nn) * LDIM + jo] = acc;
    }
}

extern "C" void kernel_launch(void* const* d_in, const int* in_sizes, int n_in,
                              void* d_out, int out_size, void* d_ws, size_t ws_size,
                              hipStream_t stream) {
    const float* x    = (const float*)d_in[0];
    const float* Wih0 = (const float*)d_in[1];
    const float* Whh0 = (const float*)d_in[2];
    const float* bih0 = (const float*)d_in[3];
    const float* bhh0 = (const float*)d_in[4];
    const float* Wih1 = (const float*)d_in[5];
    const float* Whh1 = (const float*)d_in[6];
    const float* bih1 = (const float*)d_in[7];
    const float* bhh1 = (const float*)d_in[8];
    const float* Wih2 = (const float*)d_in[9];
    const float* Whh2 = (const float*)d_in[10];
    const float* bih2 = (const float*)d_in[11];
    const float* bhh2 = (const float*)d_in[12];
    const float* Wm   = (const float*)d_in[13];
    const float* bm   = (const float*)d_in[14];
    const float* Wlv  = (const float*)d_in[15];
    const float* blv  = (const float*)d_in[16];
    float* out = (float*)d_out;

    lstm_encoder_kernel<<<dim3(BATCH / NB), dim3(NT), 0, stream>>>(
        x, Wih0, Whh0, bih0, bhh0, Wih1, Whh1, bih1, bhh1,
        Wih2, Whh2, bih2, bhh2, Wm, bm, Wlv, blv, out);
}